// Round 1
// baseline (242.198 us; speedup 1.0000x reference)
//
#include <hip/hip_runtime.h>
#include <cstddef>

// Problem constants (B,C,H,W)=(4,3,512,512), E=192, p=2 -> grid 256x256, K=12.
constexpr int kH  = 512, kW = 512, kC = 3;
constexpr int kHH = 256, kWW = 256;
constexpr int kN  = kHH * kWW;
constexpr int kE  = 192, kK = 12, kB = 4;

__device__ __forceinline__ float dinvf(int i, int j) {
    // in-degree incl. self-loop: interior 5, edge 4, corner 3
    int deg = 1 + (i > 0) + (i < kHH - 1) + (j > 0) + (j < kWW - 1);
    return rsqrtf((float)deg);
}

// M[e][k] = sum_j gcn_w[e][j] * conv_w[j][k]   (conv_w flattened [192][12])
// One 64-lane wave per output row e; shuffle reduction.
__global__ __launch_bounds__(64) void build_M(const float* __restrict__ gcn_w,
                                              const float* __restrict__ conv_w,
                                              float* __restrict__ M) {
    const int e = blockIdx.x;
    const int lane = threadIdx.x;
    float acc[kK];
#pragma unroll
    for (int k = 0; k < kK; ++k) acc[k] = 0.f;
    for (int j = lane; j < kE; j += 64) {
        const float g = gcn_w[e * kE + j];
        const float4 c0 = *(const float4*)(conv_w + j * kK + 0);
        const float4 c1 = *(const float4*)(conv_w + j * kK + 4);
        const float4 c2 = *(const float4*)(conv_w + j * kK + 8);
        acc[0] += g * c0.x; acc[1] += g * c0.y; acc[2]  += g * c0.z; acc[3]  += g * c0.w;
        acc[4] += g * c1.x; acc[5] += g * c1.y; acc[6]  += g * c1.z; acc[7]  += g * c1.w;
        acc[8] += g * c2.x; acc[9] += g * c2.y; acc[10] += g * c2.z; acc[11] += g * c2.w;
    }
#pragma unroll
    for (int k = 0; k < kK; ++k) {
        float v = acc[k];
#pragma unroll
        for (int off = 32; off > 0; off >>= 1) v += __shfl_down(v, off);
        if (lane == 0) M[e * kK + k] = v;
    }
}

// Fused: aggp[n] = dinv(n)*(dinv(n)*patch[n] + sum_nbr dinv(m)*patch[m]) in LDS,
// then out[n] = M * aggp[n] + bias, M held in registers (fixed e per thread).
constexpr int TI = 8, TJ = 8, TNODES = TI * TJ;  // 64 nodes / block
constexpr int THREADS = 192;                      // 48 e4-groups x 4 node-subs

__global__ __launch_bounds__(THREADS) void fused_gcn(
        const float* __restrict__ x, const float* __restrict__ M,
        const float* __restrict__ bias, float* __restrict__ out) {
    __shared__ float s_aggp[TNODES][kK];  // 3 KB

    const int t = threadIdx.x;
    const int nbj = kWW / TJ;  // 32
    const int nbi = kHH / TI;  // 32
    const int blk = blockIdx.x;
    const int bj = blk % nbj;
    const int bi = (blk / nbj) % nbi;
    const int b  = blk / (nbj * nbi);
    const int i0 = bi * TI, j0 = bj * TJ;

    // Per-thread fixed 4 output channels: M rows e..e+3 (48 floats) -> registers.
    const int e4  = t % 48;
    const int sub = t / 48;  // 0..3
    const int e   = e4 * 4;
    float4 mrow[12];
#pragma unroll
    for (int r = 0; r < 12; ++r) mrow[r] = ((const float4*)(M + (size_t)e * kK))[r];
    const float4 bv = *(const float4*)(bias + e);

    // ---- Phase 1: normalized-adjacency-aggregated patch vectors -> LDS
#pragma unroll
    for (int q = 0; q < (TNODES * kK) / THREADS; ++q) {  // 4 entries/thread
        const int entry = t + q * THREADS;
        const int nl = entry / kK;
        const int k  = entry % kK;
        const int i = i0 + nl / TJ;
        const int j = j0 + nl % TJ;
        const int c = k >> 2, u = (k >> 1) & 1, v = k & 1;
        const float* xb = x + ((size_t)(b * kC + c) * kH + u) * kW + v;
        const float dc = dinvf(i, j);
        float sum = dc * xb[(2 * i) * kW + 2 * j];
        if (i > 0)       sum += dinvf(i - 1, j) * xb[(2 * i - 2) * kW + 2 * j];
        if (i < kHH - 1) sum += dinvf(i + 1, j) * xb[(2 * i + 2) * kW + 2 * j];
        if (j > 0)       sum += dinvf(i, j - 1) * xb[(2 * i) * kW + 2 * j - 2];
        if (j < kWW - 1) sum += dinvf(i, j + 1) * xb[(2 * i) * kW + 2 * j + 2];
        s_aggp[nl][k] = dc * sum;
    }
    __syncthreads();

    // ---- Phase 2: project 12 -> 192, coalesced float4 stores
#pragma unroll 4
    for (int it = 0; it < TNODES / 4; ++it) {
        const int nl = it * 4 + sub;
        const float4 a0 = *((const float4*)&s_aggp[nl][0]);
        const float4 a1 = *((const float4*)&s_aggp[nl][4]);
        const float4 a2 = *((const float4*)&s_aggp[nl][8]);
        float4 acc;
        float* accp = (float*)&acc;
#pragma unroll
        for (int r = 0; r < 4; ++r) {
            const float4 m0 = mrow[r * 3 + 0];
            const float4 m1 = mrow[r * 3 + 1];
            const float4 m2 = mrow[r * 3 + 2];
            float s = ((const float*)&bv)[r];
            s += m0.x * a0.x + m0.y * a0.y + m0.z * a0.z + m0.w * a0.w;
            s += m1.x * a1.x + m1.y * a1.y + m1.z * a1.z + m1.w * a1.w;
            s += m2.x * a2.x + m2.y * a2.y + m2.z * a2.z + m2.w * a2.w;
            accp[r] = s;
        }
        const int i = i0 + nl / TJ;
        const int j = j0 + nl % TJ;
        const size_t n = (size_t)i * kWW + j;
        float4* op = (float4*)(out + ((size_t)b * kN + n) * kE + e);
        *op = acc;
    }
}

extern "C" void kernel_launch(void* const* d_in, const int* in_sizes, int n_in,
                              void* d_out, int out_size, void* d_ws, size_t ws_size,
                              hipStream_t stream) {
    const float* x      = (const float*)d_in[0];  // [4,3,512,512]
    const float* conv_w = (const float*)d_in[1];  // [192,3,2,2] -> [192][12]
    const float* gcn_w  = (const float*)d_in[2];  // [192,192]
    const float* gcn_b  = (const float*)d_in[3];  // [192]
    float* out = (float*)d_out;                   // [4, 65536, 192] fp32
    float* M   = (float*)d_ws;                    // 2304 floats = 9216 B

    build_M<<<kE, 64, 0, stream>>>(gcn_w, conv_w, M);
    fused_gcn<<<kB * (kHH / TI) * (kWW / TJ), THREADS, 0, stream>>>(x, M, gcn_b, out);
}

// Round 5
// 230.762 us; speedup vs baseline: 1.0496x; 1.0496x over previous
//
#include <hip/hip_runtime.h>
#include <cstddef>

// Problem constants (B,C,H,W)=(4,3,512,512), E=192, p=2 -> grid 256x256, K=12.
// R4: fix compile error — __builtin_nontemporal_store needs a clang ext_vector
// type, not HIP's float4 class.
constexpr int kH  = 512, kW = 512, kC = 3;
constexpr int kHH = 256, kWW = 256;
constexpr int kN  = kHH * kWW;
constexpr int kE  = 192, kK = 12, kB = 4;

typedef float nt_f4 __attribute__((ext_vector_type(4)));

__device__ __forceinline__ float dinvf(int i, int j) {
    // in-degree incl. self-loop: interior 5, edge 4, corner 3
    int deg = 1 + (i > 0) + (i < kHH - 1) + (j > 0) + (j < kWW - 1);
    return rsqrtf((float)deg);
}

// M[e][k] = sum_j gcn_w[e][j] * conv_w[j][k]   (conv_w flattened [192][12])
__global__ __launch_bounds__(64) void build_M(const float* __restrict__ gcn_w,
                                              const float* __restrict__ conv_w,
                                              float* __restrict__ M) {
    const int e = blockIdx.x;
    const int lane = threadIdx.x;
    float acc[kK];
#pragma unroll
    for (int k = 0; k < kK; ++k) acc[k] = 0.f;
    for (int j = lane; j < kE; j += 64) {
        const float g = gcn_w[e * kE + j];
        const float4 c0 = *(const float4*)(conv_w + j * kK + 0);
        const float4 c1 = *(const float4*)(conv_w + j * kK + 4);
        const float4 c2 = *(const float4*)(conv_w + j * kK + 8);
        acc[0] += g * c0.x; acc[1] += g * c0.y; acc[2]  += g * c0.z; acc[3]  += g * c0.w;
        acc[4] += g * c1.x; acc[5] += g * c1.y; acc[6]  += g * c1.z; acc[7]  += g * c1.w;
        acc[8] += g * c2.x; acc[9] += g * c2.y; acc[10] += g * c2.z; acc[11] += g * c2.w;
    }
#pragma unroll
    for (int k = 0; k < kK; ++k) {
        float v = acc[k];
#pragma unroll
        for (int off = 32; off > 0; off >>= 1) v += __shfl_down(v, off);
        if (lane == 0) M[e * kK + k] = v;
    }
}

// Row-strip fused kernel: one block = one node row i (256 nodes) of one batch b.
// Phase 0: stage 6 pixel rows x 3 ch of x into LDS (coalesced float4).
// Phase 1: aggp[j][k] = dinv(i,j) * sum over (A+I) of dinv*patch, from LDS.
// Phase 2: out[n] = M * aggp[n] + bias; M register-resident (4 rows/thread).
constexpr int THREADS = 192;
constexpr int ROWPAD  = 516;   // 512 + 4: keeps float4 alignment, spreads banks

__global__ __launch_bounds__(THREADS) void fused_gcn(
        const float* __restrict__ x, const float* __restrict__ M,
        const float* __restrict__ bias, float* __restrict__ out) {
    __shared__ float s_x[kC][6][ROWPAD];     // 36.3 KB
    __shared__ float s_aggp[kWW][kK];        // 12.3 KB

    const int t = threadIdx.x;
    const int i = blockIdx.x % kHH;
    const int b = blockIdx.x / kHH;

    // Per-thread fixed output channels e..e+3; M rows -> registers.
    const int e4  = t % 48;
    const int sub = t / 48;   // 0..3
    const int e   = e4 * 4;
    float4 mrow[12];
#pragma unroll
    for (int r = 0; r < 12; ++r) mrow[r] = ((const float4*)(M + (size_t)e * kK))[r];
    const float4 bv = *(const float4*)(bias + e);

    // ---- Phase 0: coalesced staging of pixel rows 2i-2 .. 2i+3, all 3 channels
    const int r0 = 2 * i - 2;
#pragma unroll
    for (int q = 0; q < 12; ++q) {             // 2304 float4 / 192 threads
        const int idx  = t + q * THREADS;
        const int cr   = idx >> 7;             // 0..17 = c*6 + row
        const int col4 = idx & 127;
        const int c = cr / 6, row = cr % 6;
        const int rg = r0 + row;
        float4 val = make_float4(0.f, 0.f, 0.f, 0.f);
        if (rg >= 0 && rg < kH)
            val = *(const float4*)(x + (((size_t)(b * kC + c) * kH + rg) * kW) + col4 * 4);
        *(float4*)&s_x[c][row][col4 * 4] = val;
    }
    __syncthreads();

    // ---- Phase 1: normalized aggregation (halo rows are zero at i-boundaries)
#pragma unroll
    for (int q = 0; q < 16; ++q) {             // 3072 entries / 192 threads
        const int idx = t + q * THREADS;
        const int j   = idx / kK;
        const int k   = idx % kK;
        const int c = k >> 2, u = (k >> 1) & 1, v = k & 1;
        const int col = 2 * j + v;
        const float dc = dinvf(i, j);
        const float du = dinvf(i - 1, j);
        const float dd = dinvf(i + 1, j);
        float sum = dc * s_x[c][u + 2][col]
                  + du * s_x[c][u][col]          // zero row when i==0
                  + dd * s_x[c][u + 4][col];     // zero row when i==255
        if (j > 0)       sum += dinvf(i, j - 1) * s_x[c][u + 2][col - 2];
        if (j < kWW - 1) sum += dinvf(i, j + 1) * s_x[c][u + 2][col + 2];
        s_aggp[j][k] = dc * sum;
    }
    __syncthreads();

    // ---- Phase 2: project 12 -> 192, contiguous 196 KB store per block
    float* outb = out + ((size_t)b * kN + (size_t)i * kWW) * kE + e;
#pragma unroll 4
    for (int it = 0; it < kWW / 4; ++it) {
        const int nl = it * 4 + sub;
        const float4 a0 = *((const float4*)&s_aggp[nl][0]);
        const float4 a1 = *((const float4*)&s_aggp[nl][4]);
        const float4 a2 = *((const float4*)&s_aggp[nl][8]);
        nt_f4 acc;
#pragma unroll
        for (int r = 0; r < 4; ++r) {
            const float4 m0 = mrow[r * 3 + 0];
            const float4 m1 = mrow[r * 3 + 1];
            const float4 m2 = mrow[r * 3 + 2];
            float s = ((const float*)&bv)[r];
            s += m0.x * a0.x + m0.y * a0.y + m0.z * a0.z + m0.w * a0.w;
            s += m1.x * a1.x + m1.y * a1.y + m1.z * a1.z + m1.w * a1.w;
            s += m2.x * a2.x + m2.y * a2.y + m2.z * a2.z + m2.w * a2.w;
            acc[r] = s;
        }
        __builtin_nontemporal_store(acc, (nt_f4*)(outb + (size_t)nl * kE));
    }
}

extern "C" void kernel_launch(void* const* d_in, const int* in_sizes, int n_in,
                              void* d_out, int out_size, void* d_ws, size_t ws_size,
                              hipStream_t stream) {
    const float* x      = (const float*)d_in[0];  // [4,3,512,512]
    const float* conv_w = (const float*)d_in[1];  // [192,3,2,2] -> [192][12]
    const float* gcn_w  = (const float*)d_in[2];  // [192,192]
    const float* gcn_b  = (const float*)d_in[3];  // [192]
    float* out = (float*)d_out;                   // [4, 65536, 192] fp32
    float* M   = (float*)d_ws;                    // 2304 floats

    build_M<<<kE, 64, 0, stream>>>(gcn_w, conv_w, M);
    fused_gcn<<<kB * kHH, THREADS, 0, stream>>>(x, M, gcn_b, out);
}